// Round 4
// baseline (264.100 us; speedup 1.0000x reference)
//
#include <hip/hip_runtime.h>
#include <math.h>

// HuberEMA: y[t] = y[t-1] + (1-a[c]) * clamp(x[t]-y[t-1], -d, +d); y[0] = x[0]
// B=32, T=2048, C=512 fp32. 16384 chains -> 256 blocks x 64 lanes (1 wave/CU,
// structural). Roofline: 268 MB => ~43 us @ 6.3 TB/s.
//
// R3 post-mortem: 232 us (1.15 TB/s). Cause: dword-per-lane accesses gave only
// 256 B per VMEM instruction; the 63-deep vmcnt queue then caps in-flight bytes
// at ~8 KB/wave (2 MB device) -> latency-bound, worsened by NT-store in-order
// retirement. Fix: load x as dwordx4 ACROSS channels/time (1 KB/wave-instr,
// 16 KB/wave in flight), redistribute to chain-per-lane layout via LDS.
// No nontemporal hints this round (single-variable change discipline).
//
// Per 64-t tile (per wave):  16 global dwordx4 -> regs (prefetch, dist 1)
//   -> 16 ds_write_b128 (linear, conflict-free) -> LDS [t][ch]
//   -> 64 ds_read_b32 (2-way bank alias = free) -> 64-step recurrence
//   -> 64 scalar y stores (256 B/wave, coalesced; stores are fire-and-forget).
// All register arrays statically indexed (full unroll) - no scratch.

#define TT   2048
#define CC   512
#define TILE 64
#define NTIL (TT / TILE)   // 32 tiles

__global__ __launch_bounds__(64, 1)
void huber_ema_kernel(const float* __restrict__ x,
                      const float* __restrict__ logit_alpha,
                      const float* __restrict__ delta,
                      float* __restrict__ y)
{
    const int blk  = blockIdx.x;     // 0..255
    const int b    = blk >> 3;       // batch
    const int cc   = blk & 7;        // 64-wide channel chunk
    const int lane = threadIdx.x;    // 0..63

    // per-chain alpha: a = clip(sigmoid(la), 1e-4, 1-1e-4)
    const int chc = (cc << 6) + lane;
    const float la = logit_alpha[chc];
    float a = 1.0f / (1.0f + expf(-la));
    a = fminf(fmaxf(a, 1e-4f), 1.0f - 1e-4f);
    const float oma = 1.0f - a;
    const float d = delta[0];

    const float* __restrict__ xb = x + (size_t)b * TT * CC + (cc << 6);
    float*       __restrict__ yb = y + (size_t)b * TT * CC + (cc << 6);

    // packed-load mapping: lane covers t_loc = lane>>4 within each 4-t group,
    // channels (lane&15)*4 .. +3  -> one dwordx4 per lane per 4 timesteps.
    const int tl = lane >> 4;
    const int c4 = (lane & 15) << 2;
    const float* __restrict__ xl = xb + (size_t)tl * CC + c4;

    // [t_in_tile][ch] tile, double-buffered: 2 x 16 KB
    __shared__ float lds[2][TILE * 64];

    float4 xr[16];     // staged tile (1 KB/wave per element's instruction)
    float  xin[TILE];  // this lane's chain inputs for current tile

    // y chain init: yv = x[t=0]; step 0 then computes r=0 -> y0 = x0 exactly.
    float yv = xb[lane];

    // prologue: tile 0 -> regs -> lds[0]; tile 1 -> regs
    #pragma unroll
    for (int g = 0; g < 16; ++g)
        xr[g] = *(const float4*)(xl + (size_t)(g * 4) * CC);
    #pragma unroll
    for (int g = 0; g < 16; ++g)
        *(float4*)&lds[0][g * 256 + (lane << 2)] = xr[g];
    #pragma unroll
    for (int g = 0; g < 16; ++g)
        xr[g] = *(const float4*)(xl + (size_t)(TILE + g * 4) * CC);

    for (int k = 0; k < NTIL; ++k) {
        float* __restrict__ buf  = lds[k & 1];        // holds tile k
        float* __restrict__ bufn = lds[(k + 1) & 1];

        // stage tile k+1 regs -> LDS (waits on its global loads, issued one
        // full compute-phase (~1300 cyc > HBM latency) ago)
        if (k + 1 < NTIL) {
            #pragma unroll
            for (int g = 0; g < 16; ++g)
                *(float4*)&bufn[g * 256 + (lane << 2)] = xr[g];
        }
        // issue tile k+2 global loads early (overlap with this tile's compute)
        if (k + 2 < NTIL) {
            #pragma unroll
            for (int g = 0; g < 16; ++g)
                xr[g] = *(const float4*)(xl + (size_t)((k + 2) * TILE + g * 4) * CC);
        }

        // LDS -> per-chain registers: lane reads [t][lane], 64 consecutive
        // words per wave access = 2-way bank alias = free
        #pragma unroll
        for (int i = 0; i < TILE; ++i)
            xin[i] = buf[i * 64 + lane];

        // recurrence + coalesced scalar stores (256 B/wave per t)
        const size_t tb = (size_t)k * TILE;
        #pragma unroll
        for (int i = 0; i < TILE; ++i) {
            float r = xin[i] - yv;
            yv += oma * fminf(fmaxf(r, -d), d);
            yb[(tb + (size_t)i) * CC + lane] = yv;
        }
    }
}

extern "C" void kernel_launch(void* const* d_in, const int* in_sizes, int n_in,
                              void* d_out, int out_size, void* d_ws, size_t ws_size,
                              hipStream_t stream) {
    const float* x  = (const float*)d_in[0];
    const float* la = (const float*)d_in[1];
    const float* dl = (const float*)d_in[2];
    float* y = (float*)d_out;

    huber_ema_kernel<<<dim3(256), dim3(64), 0, stream>>>(x, la, dl, y);
}